// Round 15
// baseline (500.704 us; speedup 1.0000x reference)
//
#include <hip/hip_runtime.h>
#include <hip/hip_bf16.h>
#include <cstdint>

// Problem constants (fixed by the reference)
#define NN 10000      // nodes
#define NE 320000     // edges
#define NC 256        // node channels
#define OC 512        // out channels
#define K1 256        // K for edge gemm (ea) and pq gemm (x)

typedef __bf16 bf16_t;
typedef bf16_t bf16x8 __attribute__((ext_vector_type(8)));
typedef bf16_t bf16x4 __attribute__((ext_vector_type(4)));
typedef float  f32x4  __attribute__((ext_vector_type(4)));

// async global->LDS, 16B per lane; LDS dest = wave-uniform base + lane*16
__device__ __forceinline__ void gload_lds16(const void* g, void* l) {
  __builtin_amdgcn_global_load_lds(
      (const __attribute__((address_space(1))) unsigned int*)g,
      (__attribute__((address_space(3))) unsigned int*)l, 16, 0, 0);
}

// B-side column interleave: LDS tile row R holds the weight row for logical
// column (R&~63) + (R&15)*4 + ((R>>4)&3)  ->  each lane's 4 MFMA fragments
// cover 4 CONSECUTIVE output columns (vector epilogue).
__device__ __forceinline__ int permB(int R) {
  return (R & ~63) + ((R & 15) << 2) + ((R >> 4) & 3);
}

// ---------------------------------------------------------------------------
// Prep: zero agg/deg/cursor/sums, xb=bf16(x), build transposed bf16 weights.
// ---------------------------------------------------------------------------
__global__ void k_prep(const float* __restrict__ x,
                       const float* __restrict__ W1,
                       const float* __restrict__ W2,
                       bf16_t* __restrict__ xb,
                       bf16_t* __restrict__ w1abt,
                       bf16_t* __restrict__ w1ct,
                       bf16_t* __restrict__ w2t,
                       float* __restrict__ agg,
                       int* __restrict__ deg,
                       int* __restrict__ cursor,
                       float* __restrict__ sums) {
  const int stride = gridDim.x * blockDim.x;
  for (int i = blockIdx.x * blockDim.x + threadIdx.x; i < NN * OC; i += stride) {
    agg[i] = 0.0f;
    if (i < NN * NC) xb[i] = (bf16_t)x[i];
    if (i < 1024 * K1) {
      const int n = i >> 8, k = i & 255;
      float w;
      if (n < OC) w = W1[(size_t)k * OC + n] - W1[(size_t)(k + NC) * OC + n];
      else        w = W1[(size_t)(k + NC) * OC + (n - OC)];
      w1abt[i] = (bf16_t)w;
    }
    if (i < OC * K1) {
      const int n = i >> 8, k = i & 255;
      w1ct[i] = (bf16_t)W1[(size_t)(512 + k) * OC + n];
    }
    if (i < OC * OC) {
      const int n = i >> 9, k = i & 511;
      w2t[i] = (bf16_t)W2[(size_t)k * OC + n];
    }
    if (i < NN) { deg[i] = 0; cursor[i] = 0; }
    if (i < 1024) sums[i] = 0.0f;
  }
}

__global__ void k_deg(const int* __restrict__ dstIdx, int* __restrict__ deg) {
  const int i = blockIdx.x * blockDim.x + threadIdx.x;
  if (i < NE) atomicAdd(&deg[dstIdx[i]], 1);
}

// Single-block exclusive prefix sum over NN bins.
__global__ void k_scan(const int* __restrict__ deg, int* __restrict__ offs) {
  __shared__ int carry;
  __shared__ int wsum[4];
  if (threadIdx.x == 0) carry = 0;
  __syncthreads();
  const int lane = threadIdx.x & 63, w = threadIdx.x >> 6;
  for (int base = 0; base < NN; base += 256) {
    const int i = base + threadIdx.x;
    const int v = (i < NN) ? deg[i] : 0;
    int s = v;
#pragma unroll
    for (int d = 1; d < 64; d <<= 1) { int t = __shfl_up(s, d); if (lane >= d) s += t; }
    if (lane == 63) wsum[w] = s;
    __syncthreads();
    int woff = 0;
    for (int j = 0; j < w; j++) woff += wsum[j];
    const int incl = s + woff + carry;
    if (i < NN) offs[i] = incl - v;  // exclusive
    __syncthreads();
    if (threadIdx.x == 255) carry = incl;
    __syncthreads();
  }
}

// Counting-sort scatter: edges grouped by dst.
__global__ void k_scatter(const int* __restrict__ srcIdx, const int* __restrict__ dstIdx,
                          const int* __restrict__ offs, int* __restrict__ cursor,
                          int* __restrict__ eperm, int* __restrict__ sdst,
                          int* __restrict__ ssrc) {
  const int e = blockIdx.x * blockDim.x + threadIdx.x;
  if (e < NE) {
    const int d = dstIdx[e];
    const int pos = offs[d] + atomicAdd(&cursor[d], 1);
    eperm[pos] = e;
    sdst[pos] = d;
    ssrc[pos] = srcIdx[e];
  }
}

// ---------------------------------------------------------------------------
// Node-level PQ GEMM: [P | Q] = xb @ w1abt^T.  M=10000, K=256, N=1024.
// ---------------------------------------------------------------------------
__global__ __launch_bounds__(256) void k_pq(
    const bf16_t* __restrict__ xb,     // [NN][256]
    const bf16_t* __restrict__ w1abt,  // [1024][256]
    const float*  __restrict__ b1,
    float*        __restrict__ P,      // [NN][512] fp32 (= x@W1a' + b1)
    bf16_t*       __restrict__ Qb) {   // [NN][512] bf16 (= x@W1b)
  __shared__ bf16_t sA[128 * 64];
  __shared__ bf16_t sB[128 * 64];

  const int tid = threadIdx.x;
  const int cb = blockIdx.x & 7, rblk = blockIdx.x >> 3;
  const int r0 = rblk * 128, n0 = cb * 128;
  const int lane = tid & 63, wid = tid >> 6;
  const int mbase = (wid >> 1) * 64, nbase = (wid & 1) * 64;
  const int lr = lane >> 3, ls = lane & 7, slog = ls ^ lr;
  const int g = lane >> 4;

  f32x4 acc[4][4];
#pragma unroll
  for (int mi = 0; mi < 4; mi++)
#pragma unroll
    for (int ni = 0; ni < 4; ni++) acc[mi][ni] = (f32x4){0.f, 0.f, 0.f, 0.f};

  for (int kb = 0; kb < K1; kb += 64) {
#pragma unroll
    for (int i = 0; i < 4; i++) {
      const int row = wid * 32 + i * 8;          // wave-uniform
      int grow = r0 + row + lr;                  // per-lane source row
      if (grow > NN - 1) grow = NN - 1;          // clamp (guarded on write)
      gload_lds16(xb + (size_t)grow * NC + kb + slog * 8, &sA[row * 64]);
      gload_lds16(w1abt + (size_t)(n0 + permB(row + lr)) * K1 + kb + slog * 8,
                  &sB[row * 64]);
    }
    __syncthreads();
#pragma unroll
    for (int kk = 0; kk < 2; kk++) {
      const int sl = kk * 4 + g;
      bf16x8 av[4], bv[4];
#pragma unroll
      for (int mi = 0; mi < 4; mi++) {
        const int rA = mbase + mi * 16 + (lane & 15);
        av[mi] = *(const bf16x8*)&sA[rA * 64 + ((sl ^ (rA & 7)) * 8)];
      }
#pragma unroll
      for (int ni = 0; ni < 4; ni++) {
        const int rB = nbase + ni * 16 + (lane & 15);
        bv[ni] = *(const bf16x8*)&sB[rB * 64 + ((sl ^ (rB & 7)) * 8)];
      }
#pragma unroll
      for (int mi = 0; mi < 4; mi++)
#pragma unroll
        for (int ni = 0; ni < 4; ni++)
          acc[mi][ni] = __builtin_amdgcn_mfma_f32_16x16x32_bf16(av[mi], bv[ni], acc[mi][ni], 0, 0, 0);
    }
    __syncthreads();
  }

  const int col0 = n0 + nbase + (lane & 15) * 4;
  f32x4 b1v = {0.f, 0.f, 0.f, 0.f};
  if (col0 < OC) b1v = *(const f32x4*)&b1[col0];
#pragma unroll
  for (int mi = 0; mi < 4; mi++) {
#pragma unroll
    for (int q = 0; q < 4; q++) {
      const int grow = r0 + mbase + mi * 16 + g * 4 + q;
      if (grow < NN) {
        if (col0 < OC) {
          f32x4 v;
#pragma unroll
          for (int j = 0; j < 4; j++) v[j] = acc[mi][j][q] + b1v[j];
          *(f32x4*)&P[(size_t)grow * OC + col0] = v;
        } else {
          bf16x4 v;
#pragma unroll
          for (int j = 0; j < 4; j++) v[j] = (bf16_t)acc[mi][j][q];
          *(bf16x4*)&Qb[(size_t)grow * OC + (col0 - OC)] = v;
        }
      }
    }
  }
}

// ---------------------------------------------------------------------------
// Edge GEMM (R7 champion, verbatim): R = ea @ W1c (K=256).  BM=128, BN=128,
// 4 waves, dbuf both tiles, 1 barrier/K-step, P/Q prologue prefetch,
// fused segreduce epilogue, XCD chunk swizzle.
// ---------------------------------------------------------------------------
__global__ __launch_bounds__(256, 2) void k_edge_gemm(
    const float*  __restrict__ ea,
    const bf16_t* __restrict__ w1ct,
    const float*  __restrict__ P,
    const bf16_t* __restrict__ Qb,
    const int*    __restrict__ eperm,
    const int*    __restrict__ sdst,
    const int*    __restrict__ ssrc,
    float*        __restrict__ agg) {
  __shared__ bf16_t sM[2][128 * 64];
  __shared__ bf16_t sW[2][128 * 64];
  __shared__ int sDst[128];
  __shared__ int sSrc[128];
  __shared__ int sE[128];

  const int bid = (blockIdx.x & 7) * 1250 + (blockIdx.x >> 3);
  const int cb = bid & 3, eblk = bid >> 2;
  const int e0 = eblk * 128, n0 = cb * 128;

  const int tid = threadIdx.x;
  if (tid < 128) {
    sDst[tid] = sdst[e0 + tid];
    sSrc[tid] = ssrc[e0 + tid];
    sE[tid]   = eperm[e0 + tid];
  }
  __syncthreads();

  const int lane = tid & 63, wid = tid >> 6;
  const int mbase = (wid >> 1) * 64, nbase = (wid & 1) * 64;
  const int g = lane >> 4, r = lane & 15;
  const int lr = lane >> 3, ls = lane & 7, slogW = ls ^ lr;
  const int mrow = tid >> 1, qd = tid & 1;
  const int msw = mrow & 7;
  const float* eaRow = ea + (size_t)sE[mrow] * NC;

#define STAGE_W(kt, b)                                                        \
  _Pragma("unroll") for (int i = 0; i < 4; i++) {                             \
    const int rowb = wid * 32 + i * 8;                                        \
    gload_lds16(w1ct + (size_t)(n0 + permB(rowb + lr)) * K1 + (kt)*64 + slogW * 8, \
                &sW[b][rowb * 64]);                                           \
  }
#define LOAD_A(kt)                                                            \
  _Pragma("unroll") for (int j = 0; j < 8; j++)                               \
      a[j] = *(const f32x4*)(eaRow + (kt)*64 + qd * 32 + j * 4);
#define WRITE_M(b)                                                            \
  _Pragma("unroll") for (int tt = 0; tt < 4; tt++) {                          \
    const int slot = qd * 4 + tt;                                             \
    bf16x8 v;                                                                 \
    _Pragma("unroll") for (int jj = 0; jj < 4; jj++) {                        \
      v[jj] = (bf16_t)a[tt * 2][jj];                                          \
      v[4 + jj] = (bf16_t)a[tt * 2 + 1][jj];                                  \
    }                                                                         \
    *(bf16x8*)&sM[b][mrow * 64 + ((slot ^ msw) * 8)] = v;                     \
  }

  f32x4 a[8];
  STAGE_W(0, 0);
  LOAD_A(0);

  const int col0 = n0 + nbase + r * 4;
  f32x4  Pp[4][4];
  bf16x4 Qp[4][4];
#pragma unroll
  for (int mi = 0; mi < 4; mi++) {
    const int rbase = mbase + mi * 16 + g * 4;
#pragma unroll
    for (int q = 0; q < 4; q++) {
      Pp[mi][q] = *(const f32x4*)&P[(size_t)sDst[rbase + q] * OC + col0];
      Qp[mi][q] = *(const bf16x4*)&Qb[(size_t)sSrc[rbase + q] * OC + col0];
    }
  }

  WRITE_M(0);

  f32x4 acc[4][4];
#pragma unroll
  for (int mi = 0; mi < 4; mi++)
#pragma unroll
    for (int ni = 0; ni < 4; ni++) acc[mi][ni] = (f32x4){0.f, 0.f, 0.f, 0.f};

#pragma unroll
  for (int t = 0; t < 4; t++) {
    const int b = t & 1;
    __syncthreads();
    if (t < 3) { STAGE_W(t + 1, b ^ 1); LOAD_A(t + 1); }
#pragma unroll
    for (int kk = 0; kk < 2; kk++) {
      const int sl = kk * 4 + g;
      bf16x8 av[4], bv[4];
#pragma unroll
      for (int mi = 0; mi < 4; mi++) {
        const int rA = mbase + mi * 16 + r;
        av[mi] = *(const bf16x8*)&sM[b][rA * 64 + ((sl ^ (rA & 7)) * 8)];
      }
#pragma unroll
      for (int ni = 0; ni < 4; ni++) {
        const int rB = nbase + ni * 16 + r;
        bv[ni] = *(const bf16x8*)&sW[b][rB * 64 + ((sl ^ (rB & 7)) * 8)];
      }
#pragma unroll
      for (int mi = 0; mi < 4; mi++)
#pragma unroll
        for (int ni = 0; ni < 4; ni++)
          acc[mi][ni] = __builtin_amdgcn_mfma_f32_16x16x32_bf16(av[mi], bv[ni], acc[mi][ni], 0, 0, 0);
    }
    if (t < 3) { WRITE_M(b ^ 1); }
  }
#undef STAGE_W
#undef LOAD_A
#undef WRITE_M

#pragma unroll
  for (int mi = 0; mi < 4; mi++) {
    const int rbase = mbase + mi * 16 + g * 4;
    const int d0 = sDst[rbase],     d1 = sDst[rbase + 1];
    const int d2 = sDst[rbase + 2], d3 = sDst[rbase + 3];
    const int headId = d0, tailId = d3;
    const bool b1q = (d1 != d0), b2q = (d2 != d1), b3q = (d3 != d2);
    const bool seen = b1q | b2q | b3q;
    bool match[3];
#pragma unroll
    for (int j = 0; j < 3; j++) {
      const int tIdj = __shfl(tailId, (lane & 15) | (j << 4));
      match[j] = (j < g) && (tIdj == headId);
    }
    const int nextHead = __shfl(headId, (lane + 16) & 63);
    const bool endsHere = (g == 3) || (nextHead != tailId);

    f32x4 v0, v1, v2, v3;
#pragma unroll
    for (int j = 0; j < 4; j++) {
      v0[j] = fmaxf(acc[mi][j][0] + Pp[mi][0][j] + (float)Qp[mi][0][j], 0.f);
      v1[j] = fmaxf(acc[mi][j][1] + Pp[mi][1][j] + (float)Qp[mi][1][j], 0.f);
      v2[j] = fmaxf(acc[mi][j][2] + Pp[mi][2][j] + (float)Qp[mi][2][j], 0.f);
      v3[j] = fmaxf(acc[mi][j][3] + Pp[mi][3][j] + (float)Qp[mi][3][j], 0.f);
    }

    f32x4 head = {0.f, 0.f, 0.f, 0.f}, run = v0;
    bool first = true;
    if (b1q) { head = run; first = false; run = v1; } else run += v1;
    if (b2q) {
      if (first) { head = run; first = false; }
      else {
        float* base = agg + (size_t)d1 * OC + col0;
#pragma unroll
        for (int j = 0; j < 4; j++) if (run[j] != 0.f) atomicAdd(base + j, run[j]);
      }
      run = v2;
    } else run += v2;
    if (b3q) {
      if (first) { head = run; first = false; }
      else {
        float* base = agg + (size_t)d2 * OC + col0;
#pragma unroll
        for (int j = 0; j < 4; j++) if (run[j] != 0.f) atomicAdd(base + j, run[j]);
      }
      run = v3;
    } else run += v3;
    const f32x4 tailSum = run;

    f32x4 inc = {0.f, 0.f, 0.f, 0.f};
#pragma unroll
    for (int jg = 0; jg < 3; jg++) {
      f32x4 ts;
#pragma unroll
      for (int c = 0; c < 4; c++) ts[c] = __shfl(tailSum[c], (lane & 15) | (jg << 4));
      if (match[jg]) inc += ts;
    }
    if (seen) {
      float* base = agg + (size_t)headId * OC + col0;
#pragma unroll
      for (int j = 0; j < 4; j++) {
        const float h = head[j] + inc[j];
        if (h != 0.f) atomicAdd(base + j, h);
      }
    }
    if (endsHere) {
      float* base = agg + (size_t)tailId * OC + col0;
#pragma unroll
      for (int j = 0; j < 4; j++) {
        const float t2 = tailSum[j] + (seen ? 0.f : inc[j]);
        if (t2 != 0.f) atomicAdd(base + j, t2);
      }
    }
  }
}

// ---------------------------------------------------------------------------
// Node GEMM + fused BN stats: out = agg @ W2 + deg * b2, and per-channel
// (sum, sumsq) reduced in-register (shfl over g) -> atomicAdd into sums.
// ---------------------------------------------------------------------------
__global__ __launch_bounds__(256) void k_node_gemm(
    const float*  __restrict__ agg,
    const bf16_t* __restrict__ w2t,
    const float*  __restrict__ b2,
    const int*    __restrict__ deg,
    float*        __restrict__ out,
    float*        __restrict__ sums) {  // [2][512]: sum, sumsq
  __shared__ bf16_t sM[128 * 72];
  __shared__ bf16_t sW[128 * 72];

  const int tid  = threadIdx.x;
  const int bid  = blockIdx.x;
  const int cb   = bid & 3;
  const int rblk = bid >> 2;
  const int r0   = rblk * 128;
  const int n0   = cb * 128;

  const int lane  = tid & 63, wid = tid >> 6;
  const int mbase = (wid >> 1) * 64, nbase = (wid & 1) * 64;
  const int se = tid >> 1;
  const int sk = (tid & 1) * 32;
  const int arow  = r0 + se;
  const bool rowok = arow < NN;

  f32x4 acc[4][4];
#pragma unroll
  for (int mi = 0; mi < 4; mi++)
#pragma unroll
    for (int ni = 0; ni < 4; ni++) acc[mi][ni] = (f32x4){0.f, 0.f, 0.f, 0.f};

  for (int kb = 0; kb < OC; kb += 64) {
    {
      bf16x8* dst = (bf16x8*)&sM[se * 72 + sk];
      if (rowok) {
        const float* pf = agg + (size_t)arow * OC + kb + sk;
        f32x4 f[8];
#pragma unroll
        for (int i = 0; i < 8; i++) f[i] = *(const f32x4*)(pf + i * 4);
#pragma unroll
        for (int i = 0; i < 4; i++) {
          bf16x8 v;
#pragma unroll
          for (int j = 0; j < 4; j++) {
            v[j]     = (bf16_t)f[2 * i][j];
            v[4 + j] = (bf16_t)f[2 * i + 1][j];
          }
          dst[i] = v;
        }
      } else {
        bf16x8 z = {};
        dst[0] = z; dst[1] = z; dst[2] = z; dst[3] = z;
      }
    }
    {
      const bf16_t* pw = w2t + (size_t)(n0 + permB(se)) * OC + kb + sk;
      bf16x8* dst = (bf16x8*)&sW[se * 72 + sk];
      dst[0] = *(const bf16x8*)(pw);
      dst[1] = *(const bf16x8*)(pw + 8);
      dst[2] = *(const bf16x8*)(pw + 16);
      dst[3] = *(const bf16x8*)(pw + 24);
    }
    __syncthreads();
#pragma unroll
    for (int kk = 0; kk < 2; kk++) {
      const int krd = kk * 32 + (lane >> 4) * 8;
      bf16x8 av[4], bv[4];
#pragma unroll
      for (int mi = 0; mi < 4; mi++)
        av[mi] = *(const bf16x8*)&sM[(mbase + mi * 16 + (lane & 15)) * 72 + krd];
#pragma unroll
      for (int ni = 0; ni < 4; ni++)
        bv[ni] = *(const bf16x8*)&sW[(nbase + ni * 16 + (lane & 15)) * 72 + krd];
#pragma unroll
      for (int mi = 0; mi < 4; mi++)
#pragma unroll
        for (int ni = 0; ni < 4; ni++)
          acc[mi][ni] = __builtin_amdgcn_mfma_f32_16x16x32_bf16(av[mi], bv[ni], acc[mi][ni], 0, 0, 0);
    }
    __syncthreads();
  }

  const int col0 = n0 + nbase + (lane & 15) * 4;
  const f32x4 b2v = *(const f32x4*)&b2[col0];
  const int g = lane >> 4;
  f32x4 s1 = {0.f, 0.f, 0.f, 0.f}, s2 = {0.f, 0.f, 0.f, 0.f};
#pragma unroll
  for (int mi = 0; mi < 4; mi++) {
#pragma unroll
    for (int q = 0; q < 4; q++) {
      const int row = r0 + mbase + mi * 16 + g * 4 + q;
      if (row < NN) {
        const float dg = (float)deg[row];
        f32x4 v;
#pragma unroll
        for (int j = 0; j < 4; j++) {
          v[j] = acc[mi][j][q] + b2v[j] * dg;
          s1[j] += v[j];
          s2[j] += v[j] * v[j];
        }
        *(f32x4*)&out[(size_t)row * OC + col0] = v;
      }
    }
  }
  // reduce (s1,s2) over the g dimension (lanes differing in bits 4,5)
#pragma unroll
  for (int j = 0; j < 4; j++) {
    s1[j] += __shfl_xor(s1[j], 16);  s2[j] += __shfl_xor(s2[j], 16);
    s1[j] += __shfl_xor(s1[j], 32);  s2[j] += __shfl_xor(s2[j], 32);
  }
  if (g == 0) {
#pragma unroll
    for (int j = 0; j < 4; j++) {
      atomicAdd(&sums[col0 + j], s1[j]);
      atomicAdd(&sums[OC + col0 + j], s2[j]);
    }
  }
}

// ---------------------------------------------------------------------------
// BN apply (+relu), scale/shift computed inline from sums (L2-hot).
// ---------------------------------------------------------------------------
__global__ void k_bn_apply(float* __restrict__ out,
                           const float* __restrict__ sums,
                           const float* __restrict__ gamma,
                           const float* __restrict__ beta) {
  const int i = blockIdx.x * blockDim.x + threadIdx.x;  // float4 index
  f32x4 v = *((const f32x4*)out + i);
  const int c = (i & 127) << 2;
  const f32x4 sm = *(const f32x4*)&sums[c];
  const f32x4 sq = *(const f32x4*)&sums[OC + c];
  const f32x4 gm = *(const f32x4*)&gamma[c];
  const f32x4 bt = *(const f32x4*)&beta[c];
  f32x4 r;
#pragma unroll
  for (int j = 0; j < 4; j++) {
    const float mean = sm[j] * (1.0f / NN);
    const float var  = sq[j] * (1.0f / NN) - mean * mean;
    const float sc   = rsqrtf(var + 1e-5f) * gm[j];
    r[j] = fmaxf(v[j] * sc + (bt[j] - mean * sc), 0.0f);
  }
  *((f32x4*)out + i) = r;
}

// ---------------------------------------------------------------------------
extern "C" void kernel_launch(void* const* d_in, const int* in_sizes, int n_in,
                              void* d_out, int out_size, void* d_ws, size_t ws_size,
                              hipStream_t stream) {
  const float* x     = (const float*)d_in[0];
  const int*   ei    = (const int*)d_in[1];
  const float* ea    = (const float*)d_in[2];
  const float* W1    = (const float*)d_in[3];
  const float* b1    = (const float*)d_in[4];
  const float* W2    = (const float*)d_in[5];
  const float* b2    = (const float*)d_in[6];
  const float* gamma = (const float*)d_in[7];
  const float* beta  = (const float*)d_in[8];
  float* out = (float*)d_out;

  char* ws = (char*)d_ws;
  float*  agg    = (float*)(ws);                    // 20,480,000 B
  float*  P      = (float*)(ws + 20480000);         // 20,480,000 B
  bf16_t* Qb     = (bf16_t*)(ws + 40960000);        // 10,240,000 B
  bf16_t* xb     = (bf16_t*)(ws + 51200000);        //  5,120,000 B
  bf16_t* w1abt  = (bf16_t*)(ws + 56320000);        //    524,288 B
  bf16_t* w1ct   = (bf16_t*)(ws + 56844288);        //    262,144 B
  bf16_t* w2t    = (bf16_t*)(ws + 57106432);        //    524,288 B
  int*    deg    = (int*)(ws + 57630720);           //     40,000 B
  int*    offs   = (int*)(ws + 57670720);           //     40,000 B
  int*    cursor = (int*)(ws + 57710720);           //     40,000 B
  float*  sums   = (float*)(ws + 57750720);         //      4,096 B
  int*    eperm  = (int*)(ws + 57754816);           //  1,280,000 B
  int*    sdst   = (int*)(ws + 59034816);           //  1,280,000 B
  int*    ssrc   = (int*)(ws + 60314816);           //  1,280,000 B

  const int* srcIdx = ei;
  const int* dstIdx = ei + NE;

  k_prep<<<4096, 256, 0, stream>>>(x, W1, W2, xb, w1abt, w1ct, w2t, agg, deg, cursor, sums);
  k_deg<<<(NE + 255) / 256, 256, 0, stream>>>(dstIdx, deg);
  k_scan<<<1, 256, 0, stream>>>(deg, offs);
  k_scatter<<<(NE + 255) / 256, 256, 0, stream>>>(srcIdx, dstIdx, offs, cursor,
                                                  eperm, sdst, ssrc);
  k_pq<<<((NN + 127) / 128) * 8, 256, 0, stream>>>(xb, w1abt, b1, P, Qb);
  k_edge_gemm<<<(NE / 128) * 4, 256, 0, stream>>>(ea, w1ct, P, Qb, eperm, sdst, ssrc, agg);
  k_node_gemm<<<((NN + 127) / 128) * 4, 256, 0, stream>>>(agg, w2t, b2, deg, out, sums);
  k_bn_apply<<<(NN * OC / 4 + 255) / 256, 256, 0, stream>>>(out, sums, gamma, beta);
}

// Round 16
// 423.911 us; speedup vs baseline: 1.1812x; 1.1812x over previous
//
#include <hip/hip_runtime.h>
#include <hip/hip_bf16.h>
#include <cstdint>

// Problem constants (fixed by the reference)
#define NN 10000      // nodes
#define NE 320000     // edges
#define NC 256        // node channels
#define OC 512        // out channels
#define K1 256        // K for edge gemm (ea) and pq gemm (x)

typedef __bf16 bf16_t;
typedef bf16_t bf16x8 __attribute__((ext_vector_type(8)));
typedef bf16_t bf16x4 __attribute__((ext_vector_type(4)));
typedef bf16_t bf16x2 __attribute__((ext_vector_type(2)));
typedef float  f32x4  __attribute__((ext_vector_type(4)));
typedef float  f32x2  __attribute__((ext_vector_type(2)));

// async global->LDS, 16B per lane; LDS dest = wave-uniform base + lane*16
__device__ __forceinline__ void gload_lds16(const void* g, void* l) {
  __builtin_amdgcn_global_load_lds(
      (const __attribute__((address_space(1))) unsigned int*)g,
      (__attribute__((address_space(3))) unsigned int*)l, 16, 0, 0);
}

// B-side column interleave for 4-col/lane kernels (k_pq, k_node_gemm):
// tile row R holds the weight row for logical col (R&~63)+(R&15)*4+((R>>4)&3).
__device__ __forceinline__ int permB(int R) {
  return (R & ~63) + ((R & 15) << 2) + ((R >> 4) & 3);
}
// B-side column interleave for 2-col/lane kernels (k_edge_gemm, 8-wave):
// tile row R holds the weight row for logical col (R&~31)+(R&15)*2+((R>>4)&1)
// -> lane r's 2 fragments (ni=0,1) cover 2 CONSECUTIVE output columns.
__device__ __forceinline__ int permB32(int R) {
  return (R & ~31) + ((R & 15) << 1) + ((R >> 4) & 1);
}

// ---------------------------------------------------------------------------
// Prep: zero agg/deg/cursor/sums, xb=bf16(x), build transposed bf16 weights.
// ---------------------------------------------------------------------------
__global__ void k_prep(const float* __restrict__ x,
                       const float* __restrict__ W1,
                       const float* __restrict__ W2,
                       bf16_t* __restrict__ xb,
                       bf16_t* __restrict__ w1abt,
                       bf16_t* __restrict__ w1ct,
                       bf16_t* __restrict__ w2t,
                       float* __restrict__ agg,
                       int* __restrict__ deg,
                       int* __restrict__ cursor,
                       float* __restrict__ sums) {
  const int stride = gridDim.x * blockDim.x;
  for (int i = blockIdx.x * blockDim.x + threadIdx.x; i < NN * OC; i += stride) {
    agg[i] = 0.0f;
    if (i < NN * NC) xb[i] = (bf16_t)x[i];
    if (i < 1024 * K1) {
      const int n = i >> 8, k = i & 255;
      float w;
      if (n < OC) w = W1[(size_t)k * OC + n] - W1[(size_t)(k + NC) * OC + n];
      else        w = W1[(size_t)(k + NC) * OC + (n - OC)];
      w1abt[i] = (bf16_t)w;
    }
    if (i < OC * K1) {
      const int n = i >> 8, k = i & 255;
      w1ct[i] = (bf16_t)W1[(size_t)(512 + k) * OC + n];
    }
    if (i < OC * OC) {
      const int n = i >> 9, k = i & 511;
      w2t[i] = (bf16_t)W2[(size_t)k * OC + n];
    }
    if (i < NN) { deg[i] = 0; cursor[i] = 0; }
    if (i < 1024) sums[i] = 0.0f;
  }
}

__global__ void k_deg(const int* __restrict__ dstIdx, int* __restrict__ deg) {
  const int i = blockIdx.x * blockDim.x + threadIdx.x;
  if (i < NE) atomicAdd(&deg[dstIdx[i]], 1);
}

// Single-block exclusive prefix sum over NN bins.
__global__ void k_scan(const int* __restrict__ deg, int* __restrict__ offs) {
  __shared__ int carry;
  __shared__ int wsum[4];
  if (threadIdx.x == 0) carry = 0;
  __syncthreads();
  const int lane = threadIdx.x & 63, w = threadIdx.x >> 6;
  for (int base = 0; base < NN; base += 256) {
    const int i = base + threadIdx.x;
    const int v = (i < NN) ? deg[i] : 0;
    int s = v;
#pragma unroll
    for (int d = 1; d < 64; d <<= 1) { int t = __shfl_up(s, d); if (lane >= d) s += t; }
    if (lane == 63) wsum[w] = s;
    __syncthreads();
    int woff = 0;
    for (int j = 0; j < w; j++) woff += wsum[j];
    const int incl = s + woff + carry;
    if (i < NN) offs[i] = incl - v;  // exclusive
    __syncthreads();
    if (threadIdx.x == 255) carry = incl;
    __syncthreads();
  }
}

// Counting-sort scatter: edges grouped by dst.
__global__ void k_scatter(const int* __restrict__ srcIdx, const int* __restrict__ dstIdx,
                          const int* __restrict__ offs, int* __restrict__ cursor,
                          int* __restrict__ eperm, int* __restrict__ sdst,
                          int* __restrict__ ssrc) {
  const int e = blockIdx.x * blockDim.x + threadIdx.x;
  if (e < NE) {
    const int d = dstIdx[e];
    const int pos = offs[d] + atomicAdd(&cursor[d], 1);
    eperm[pos] = e;
    sdst[pos] = d;
    ssrc[pos] = srcIdx[e];
  }
}

// ---------------------------------------------------------------------------
// Node-level PQ GEMM: [P | Q] = xb @ w1abt^T.  M=10000, K=256, N=1024.
// ---------------------------------------------------------------------------
__global__ __launch_bounds__(256) void k_pq(
    const bf16_t* __restrict__ xb,     // [NN][256]
    const bf16_t* __restrict__ w1abt,  // [1024][256]
    const float*  __restrict__ b1,
    float*        __restrict__ P,      // [NN][512] fp32 (= x@W1a' + b1)
    bf16_t*       __restrict__ Qb) {   // [NN][512] bf16 (= x@W1b)
  __shared__ bf16_t sA[128 * 64];
  __shared__ bf16_t sB[128 * 64];

  const int tid = threadIdx.x;
  const int cb = blockIdx.x & 7, rblk = blockIdx.x >> 3;
  const int r0 = rblk * 128, n0 = cb * 128;
  const int lane = tid & 63, wid = tid >> 6;
  const int mbase = (wid >> 1) * 64, nbase = (wid & 1) * 64;
  const int lr = lane >> 3, ls = lane & 7, slog = ls ^ lr;
  const int g = lane >> 4;

  f32x4 acc[4][4];
#pragma unroll
  for (int mi = 0; mi < 4; mi++)
#pragma unroll
    for (int ni = 0; ni < 4; ni++) acc[mi][ni] = (f32x4){0.f, 0.f, 0.f, 0.f};

  for (int kb = 0; kb < K1; kb += 64) {
#pragma unroll
    for (int i = 0; i < 4; i++) {
      const int row = wid * 32 + i * 8;          // wave-uniform
      int grow = r0 + row + lr;                  // per-lane source row
      if (grow > NN - 1) grow = NN - 1;          // clamp (guarded on write)
      gload_lds16(xb + (size_t)grow * NC + kb + slog * 8, &sA[row * 64]);
      gload_lds16(w1abt + (size_t)(n0 + permB(row + lr)) * K1 + kb + slog * 8,
                  &sB[row * 64]);
    }
    __syncthreads();
#pragma unroll
    for (int kk = 0; kk < 2; kk++) {
      const int sl = kk * 4 + g;
      bf16x8 av[4], bv[4];
#pragma unroll
      for (int mi = 0; mi < 4; mi++) {
        const int rA = mbase + mi * 16 + (lane & 15);
        av[mi] = *(const bf16x8*)&sA[rA * 64 + ((sl ^ (rA & 7)) * 8)];
      }
#pragma unroll
      for (int ni = 0; ni < 4; ni++) {
        const int rB = nbase + ni * 16 + (lane & 15);
        bv[ni] = *(const bf16x8*)&sB[rB * 64 + ((sl ^ (rB & 7)) * 8)];
      }
#pragma unroll
      for (int mi = 0; mi < 4; mi++)
#pragma unroll
        for (int ni = 0; ni < 4; ni++)
          acc[mi][ni] = __builtin_amdgcn_mfma_f32_16x16x32_bf16(av[mi], bv[ni], acc[mi][ni], 0, 0, 0);
    }
    __syncthreads();
  }

  const int col0 = n0 + nbase + (lane & 15) * 4;
  f32x4 b1v = {0.f, 0.f, 0.f, 0.f};
  if (col0 < OC) b1v = *(const f32x4*)&b1[col0];
#pragma unroll
  for (int mi = 0; mi < 4; mi++) {
#pragma unroll
    for (int q = 0; q < 4; q++) {
      const int grow = r0 + mbase + mi * 16 + g * 4 + q;
      if (grow < NN) {
        if (col0 < OC) {
          f32x4 v;
#pragma unroll
          for (int j = 0; j < 4; j++) v[j] = acc[mi][j][q] + b1v[j];
          *(f32x4*)&P[(size_t)grow * OC + col0] = v;
        } else {
          bf16x4 v;
#pragma unroll
          for (int j = 0; j < 4; j++) v[j] = (bf16_t)acc[mi][j][q];
          *(bf16x4*)&Qb[(size_t)grow * OC + (col0 - OC)] = v;
        }
      }
    }
  }
}

// ---------------------------------------------------------------------------
// Edge GEMM v8 (16 waves/CU): same BM=128 x BN=128 tile and R7 pipeline, but
// 512 threads (8 waves as 2M x 4N; each wave 64x32 output, acc[4][2]).
// LDS unchanged (64KB + idx) -> still 2 blocks/CU -> 16 waves/CU of latency
// cover (vs 8).  permB32 col-interleave -> each lane owns 2 consecutive
// output cols (f32x2/bf16x2 epilogue).  P/Q loaded inline in the epilogue
// (prefetch dropped to fit 4 waves/SIMD VGPR budget).
// ---------------------------------------------------------------------------
__global__ __launch_bounds__(512, 4) void k_edge_gemm(
    const float*  __restrict__ ea,
    const bf16_t* __restrict__ w1ct,
    const float*  __restrict__ P,
    const bf16_t* __restrict__ Qb,
    const int*    __restrict__ eperm,
    const int*    __restrict__ sdst,
    const int*    __restrict__ ssrc,
    float*        __restrict__ agg) {
  __shared__ bf16_t sM[2][128 * 64];   // 32 KB
  __shared__ bf16_t sW[2][128 * 64];   // 32 KB
  __shared__ int sDst[128];
  __shared__ int sSrc[128];
  __shared__ int sE[128];

  const int bid = (blockIdx.x & 7) * 1250 + (blockIdx.x >> 3);  // XCD swizzle
  const int cb = bid & 3, eblk = bid >> 2;
  const int e0 = eblk * 128, n0 = cb * 128;

  const int tid = threadIdx.x;
  if (tid < 128) {
    sDst[tid] = sdst[e0 + tid];
    sSrc[tid] = ssrc[e0 + tid];
    sE[tid]   = eperm[e0 + tid];
  }
  __syncthreads();

  const int lane = tid & 63, wid = tid >> 6;          // 8 waves
  const int mbase = (wid >> 2) * 64;                  // 2 M-groups
  const int nbase = (wid & 3) * 32;                   // 4 N-groups
  const int g = lane >> 4, r = lane & 15;
  const int lr = lane >> 3, ls = lane & 7, slogW = ls ^ lr;  // W staging
  const int mrow = tid >> 2, qd = tid & 3;            // ea: 4 thr/row, 16 k each
  const int msw = mrow & 7;
  const float* eaRow = ea + (size_t)sE[mrow] * NC;

#define STAGE_W(kt, b)                                                        \
  _Pragma("unroll") for (int i = 0; i < 2; i++) {                             \
    const int rowb = wid * 16 + i * 8;  /* wave-uniform, 8x16=128 rows */     \
    gload_lds16(w1ct + (size_t)(n0 + permB32(rowb + lr)) * K1 + (kt)*64 + slogW * 8, \
                &sW[b][rowb * 64]);                                           \
  }
#define LOAD_A(kt)                                                            \
  _Pragma("unroll") for (int j = 0; j < 4; j++)                               \
      a[j] = *(const f32x4*)(eaRow + (kt)*64 + qd * 16 + j * 4);
#define WRITE_M(b)                                                            \
  _Pragma("unroll") for (int tt = 0; tt < 2; tt++) {                          \
    const int slot = qd * 2 + tt;                                             \
    bf16x8 v;                                                                 \
    _Pragma("unroll") for (int jj = 0; jj < 4; jj++) {                        \
      v[jj] = (bf16_t)a[tt * 2][jj];                                          \
      v[4 + jj] = (bf16_t)a[tt * 2 + 1][jj];                                  \
    }                                                                         \
    *(bf16x8*)&sM[b][mrow * 64 + ((slot ^ msw) * 8)] = v;                     \
  }

  f32x4 a[4];
  STAGE_W(0, 0);
  LOAD_A(0);
  WRITE_M(0);

  f32x4 acc[4][2];
#pragma unroll
  for (int mi = 0; mi < 4; mi++)
#pragma unroll
    for (int ni = 0; ni < 2; ni++) acc[mi][ni] = (f32x4){0.f, 0.f, 0.f, 0.f};

#pragma unroll
  for (int t = 0; t < 4; t++) {
    const int b = t & 1;
    __syncthreads();
    if (t < 3) { STAGE_W(t + 1, b ^ 1); LOAD_A(t + 1); }
#pragma unroll
    for (int kk = 0; kk < 2; kk++) {
      const int sl = kk * 4 + g;
      bf16x8 av[4], bv[2];
#pragma unroll
      for (int mi = 0; mi < 4; mi++) {
        const int rA = mbase + mi * 16 + r;
        av[mi] = *(const bf16x8*)&sM[b][rA * 64 + ((sl ^ (rA & 7)) * 8)];
      }
#pragma unroll
      for (int ni = 0; ni < 2; ni++) {
        const int rB = nbase + ni * 16 + r;
        bv[ni] = *(const bf16x8*)&sW[b][rB * 64 + ((sl ^ (rB & 7)) * 8)];
      }
#pragma unroll
      for (int mi = 0; mi < 4; mi++)
#pragma unroll
        for (int ni = 0; ni < 2; ni++)
          acc[mi][ni] = __builtin_amdgcn_mfma_f32_16x16x32_bf16(av[mi], bv[ni], acc[mi][ni], 0, 0, 0);
    }
    if (t < 3) { WRITE_M(b ^ 1); }
  }
#undef STAGE_W
#undef LOAD_A
#undef WRITE_M

  // ---- epilogue: relu(acc + P[dst] + Q[src]) -> segmented reduce ----
  const int col0 = n0 + nbase + r * 2;   // 2 consecutive cols per lane
#pragma unroll
  for (int mi = 0; mi < 4; mi++) {
    const int rbase = mbase + mi * 16 + g * 4;
    const int d0 = sDst[rbase],     d1 = sDst[rbase + 1];
    const int d2 = sDst[rbase + 2], d3 = sDst[rbase + 3];
    const int s0 = sSrc[rbase],     s1 = sSrc[rbase + 1];
    const int s2 = sSrc[rbase + 2], s3 = sSrc[rbase + 3];
    const int headId = d0, tailId = d3;
    const bool b1q = (d1 != d0), b2q = (d2 != d1), b3q = (d3 != d2);
    const bool seen = b1q | b2q | b3q;
    bool match[3];
#pragma unroll
    for (int j = 0; j < 3; j++) {
      const int tIdj = __shfl(tailId, (lane & 15) | (j << 4));
      match[j] = (j < g) && (tIdj == headId);
    }
    const int nextHead = __shfl(headId, (lane + 16) & 63);
    const bool endsHere = (g == 3) || (nextHead != tailId);

    const f32x2 P0 = *(const f32x2*)&P[(size_t)d0 * OC + col0];
    const f32x2 P1 = *(const f32x2*)&P[(size_t)d1 * OC + col0];
    const f32x2 P2 = *(const f32x2*)&P[(size_t)d2 * OC + col0];
    const f32x2 P3 = *(const f32x2*)&P[(size_t)d3 * OC + col0];
    const bf16x2 Q0 = *(const bf16x2*)&Qb[(size_t)s0 * OC + col0];
    const bf16x2 Q1 = *(const bf16x2*)&Qb[(size_t)s1 * OC + col0];
    const bf16x2 Q2 = *(const bf16x2*)&Qb[(size_t)s2 * OC + col0];
    const bf16x2 Q3 = *(const bf16x2*)&Qb[(size_t)s3 * OC + col0];

    f32x2 v0, v1, v2, v3;
#pragma unroll
    for (int j = 0; j < 2; j++) {
      v0[j] = fmaxf(acc[mi][j][0] + P0[j] + (float)Q0[j], 0.f);
      v1[j] = fmaxf(acc[mi][j][1] + P1[j] + (float)Q1[j], 0.f);
      v2[j] = fmaxf(acc[mi][j][2] + P2[j] + (float)Q2[j], 0.f);
      v3[j] = fmaxf(acc[mi][j][3] + P3[j] + (float)Q3[j], 0.f);
    }

    // quad walk: head run, interior flushes, tail run (element-wise f32x2)
    f32x2 head = {0.f, 0.f}, run = v0;
    bool first = true;
    if (b1q) { head = run; first = false; run = v1; } else run += v1;
    if (b2q) {
      if (first) { head = run; first = false; }
      else {
        float* base = agg + (size_t)d1 * OC + col0;
#pragma unroll
        for (int j = 0; j < 2; j++) if (run[j] != 0.f) atomicAdd(base + j, run[j]);
      }
      run = v2;
    } else run += v2;
    if (b3q) {
      if (first) { head = run; first = false; }
      else {
        float* base = agg + (size_t)d2 * OC + col0;
#pragma unroll
        for (int j = 0; j < 2; j++) if (run[j] != 0.f) atomicAdd(base + j, run[j]);
      }
      run = v3;
    } else run += v3;
    const f32x2 tailSum = run;

    f32x2 inc = {0.f, 0.f};
#pragma unroll
    for (int jg = 0; jg < 3; jg++) {
      f32x2 ts;
#pragma unroll
      for (int c = 0; c < 2; c++) ts[c] = __shfl(tailSum[c], (lane & 15) | (jg << 4));
      if (match[jg]) inc += ts;
    }
    if (seen) {
      float* base = agg + (size_t)headId * OC + col0;
#pragma unroll
      for (int j = 0; j < 2; j++) {
        const float h = head[j] + inc[j];
        if (h != 0.f) atomicAdd(base + j, h);
      }
    }
    if (endsHere) {
      float* base = agg + (size_t)tailId * OC + col0;
#pragma unroll
      for (int j = 0; j < 2; j++) {
        const float t2 = tailSum[j] + (seen ? 0.f : inc[j]);
        if (t2 != 0.f) atomicAdd(base + j, t2);
      }
    }
  }
}

// ---------------------------------------------------------------------------
// Node GEMM + fused BN stats: out = agg @ W2 + deg * b2, per-channel
// (sum, sumsq) reduced in-register (shfl over g) -> atomicAdd into sums.
// ---------------------------------------------------------------------------
__global__ __launch_bounds__(256) void k_node_gemm(
    const float*  __restrict__ agg,
    const bf16_t* __restrict__ w2t,
    const float*  __restrict__ b2,
    const int*    __restrict__ deg,
    float*        __restrict__ out,
    float*        __restrict__ sums) {  // [2][512]: sum, sumsq
  __shared__ bf16_t sM[128 * 72];
  __shared__ bf16_t sW[128 * 72];

  const int tid  = threadIdx.x;
  const int bid  = blockIdx.x;
  const int cb   = bid & 3;
  const int rblk = bid >> 2;
  const int r0   = rblk * 128;
  const int n0   = cb * 128;

  const int lane  = tid & 63, wid = tid >> 6;
  const int mbase = (wid >> 1) * 64, nbase = (wid & 1) * 64;
  const int se = tid >> 1;
  const int sk = (tid & 1) * 32;
  const int arow  = r0 + se;
  const bool rowok = arow < NN;

  f32x4 acc[4][4];
#pragma unroll
  for (int mi = 0; mi < 4; mi++)
#pragma unroll
    for (int ni = 0; ni < 4; ni++) acc[mi][ni] = (f32x4){0.f, 0.f, 0.f, 0.f};

  for (int kb = 0; kb < OC; kb += 64) {
    {
      bf16x8* dst = (bf16x8*)&sM[se * 72 + sk];
      if (rowok) {
        const float* pf = agg + (size_t)arow * OC + kb + sk;
        f32x4 f[8];
#pragma unroll
        for (int i = 0; i < 8; i++) f[i] = *(const f32x4*)(pf + i * 4);
#pragma unroll
        for (int i = 0; i < 4; i++) {
          bf16x8 v;
#pragma unroll
          for (int j = 0; j < 4; j++) {
            v[j]     = (bf16_t)f[2 * i][j];
            v[4 + j] = (bf16_t)f[2 * i + 1][j];
          }
          dst[i] = v;
        }
      } else {
        bf16x8 z = {};
        dst[0] = z; dst[1] = z; dst[2] = z; dst[3] = z;
      }
    }
    {
      const bf16_t* pw = w2t + (size_t)(n0 + permB(se)) * OC + kb + sk;
      bf16x8* dst = (bf16x8*)&sW[se * 72 + sk];
      dst[0] = *(const bf16x8*)(pw);
      dst[1] = *(const bf16x8*)(pw + 8);
      dst[2] = *(const bf16x8*)(pw + 16);
      dst[3] = *(const bf16x8*)(pw + 24);
    }
    __syncthreads();
#pragma unroll
    for (int kk = 0; kk < 2; kk++) {
      const int krd = kk * 32 + (lane >> 4) * 8;
      bf16x8 av[4], bv[4];
#pragma unroll
      for (int mi = 0; mi < 4; mi++)
        av[mi] = *(const bf16x8*)&sM[(mbase + mi * 16 + (lane & 15)) * 72 + krd];
#pragma unroll
      for (int ni = 0; ni < 4; ni++)
        bv[ni] = *(const bf16x8*)&sW[(nbase + ni * 16 + (lane & 15)) * 72 + krd];
#pragma unroll
      for (int mi = 0; mi < 4; mi++)
#pragma unroll
        for (int ni = 0; ni < 4; ni++)
          acc[mi][ni] = __builtin_amdgcn_mfma_f32_16x16x32_bf16(av[mi], bv[ni], acc[mi][ni], 0, 0, 0);
    }
    __syncthreads();
  }

  const int col0 = n0 + nbase + (lane & 15) * 4;
  const f32x4 b2v = *(const f32x4*)&b2[col0];
  const int g = lane >> 4;
  f32x4 s1 = {0.f, 0.f, 0.f, 0.f}, s2 = {0.f, 0.f, 0.f, 0.f};
#pragma unroll
  for (int mi = 0; mi < 4; mi++) {
#pragma unroll
    for (int q = 0; q < 4; q++) {
      const int row = r0 + mbase + mi * 16 + g * 4 + q;
      if (row < NN) {
        const float dg = (float)deg[row];
        f32x4 v;
#pragma unroll
        for (int j = 0; j < 4; j++) {
          v[j] = acc[mi][j][q] + b2v[j] * dg;
          s1[j] += v[j];
          s2[j] += v[j] * v[j];
        }
        *(f32x4*)&out[(size_t)row * OC + col0] = v;
      }
    }
  }
#pragma unroll
  for (int j = 0; j < 4; j++) {
    s1[j] += __shfl_xor(s1[j], 16);  s2[j] += __shfl_xor(s2[j], 16);
    s1[j] += __shfl_xor(s1[j], 32);  s2[j] += __shfl_xor(s2[j], 32);
  }
  if (g == 0) {
#pragma unroll
    for (int j = 0; j < 4; j++) {
      atomicAdd(&sums[col0 + j], s1[j]);
      atomicAdd(&sums[OC + col0 + j], s2[j]);
    }
  }
}

// ---------------------------------------------------------------------------
// BN apply (+relu), scale/shift computed inline from sums (L2-hot).
// ---------------------------------------------------------------------------
__global__ void k_bn_apply(float* __restrict__ out,
                           const float* __restrict__ sums,
                           const float* __restrict__ gamma,
                           const float* __restrict__ beta) {
  const int i = blockIdx.x * blockDim.x + threadIdx.x;  // float4 index
  f32x4 v = *((const f32x4*)out + i);
  const int c = (i & 127) << 2;
  const f32x4 sm = *(const f32x4*)&sums[c];
  const f32x4 sq = *(const f32x4*)&sums[OC + c];
  const f32x4 gm = *(const f32x4*)&gamma[c];
  const f32x4 bt = *(const f32x4*)&beta[c];
  f32x4 r;
#pragma unroll
  for (int j = 0; j < 4; j++) {
    const float mean = sm[j] * (1.0f / NN);
    const float var  = sq[j] * (1.0f / NN) - mean * mean;
    const float sc   = rsqrtf(var + 1e-5f) * gm[j];
    r[j] = fmaxf(v[j] * sc + (bt[j] - mean * sc), 0.0f);
  }
  *((f32x4*)out + i) = r;
}

// ---------------------------------------------------------------------------
extern "C" void kernel_launch(void* const* d_in, const int* in_sizes, int n_in,
                              void* d_out, int out_size, void* d_ws, size_t ws_size,
                              hipStream_t stream) {
  const float* x     = (const float*)d_in[0];
  const int*   ei    = (const int*)d_in[1];
  const float* ea    = (const float*)d_in[2];
  const float* W1    = (const float*)d_in[3];
  const float* b1    = (const float*)d_in[4];
  const float* W2    = (const float*)d_in[5];
  const float* b2    = (const float*)d_in[6];
  const float* gamma = (const float*)d_in[7];
  const float* beta  = (const float*)d_in[8];
  float* out = (float*)d_out;

  char* ws = (char*)d_ws;
  float*  agg    = (float*)(ws);                    // 20,480,000 B
  float*  P      = (float*)(ws + 20480000);         // 20,480,000 B
  bf16_t* Qb     = (bf16_t*)(ws + 40960000);        // 10,240,000 B
  bf16_t* xb     = (bf16_t*)(ws + 51200000);        //  5,120,000 B
  bf16_t* w1abt  = (bf16_t*)(ws + 56320000);        //    524,288 B
  bf16_t* w1ct   = (bf16_t*)(ws + 56844288);        //    262,144 B
  bf16_t* w2t    = (bf16_t*)(ws + 57106432);        //    524,288 B
  int*    deg    = (int*)(ws + 57630720);           //     40,000 B
  int*    offs   = (int*)(ws + 57670720);           //     40,000 B
  int*    cursor = (int*)(ws + 57710720);           //     40,000 B
  float*  sums   = (float*)(ws + 57750720);         //      4,096 B
  int*    eperm  = (int*)(ws + 57754816);           //  1,280,000 B
  int*    sdst   = (int*)(ws + 59034816);           //  1,280,000 B
  int*    ssrc   = (int*)(ws + 60314816);           //  1,280,000 B

  const int* srcIdx = ei;
  const int* dstIdx = ei + NE;

  k_prep<<<4096, 256, 0, stream>>>(x, W1, W2, xb, w1abt, w1ct, w2t, agg, deg, cursor, sums);
  k_deg<<<(NE + 255) / 256, 256, 0, stream>>>(dstIdx, deg);
  k_scan<<<1, 256, 0, stream>>>(deg, offs);
  k_scatter<<<(NE + 255) / 256, 256, 0, stream>>>(srcIdx, dstIdx, offs, cursor,
                                                  eperm, sdst, ssrc);
  k_pq<<<((NN + 127) / 128) * 8, 256, 0, stream>>>(xb, w1abt, b1, P, Qb);
  k_edge_gemm<<<(NE / 128) * 4, 512, 0, stream>>>(ea, w1ct, P, Qb, eperm, sdst, ssrc, agg);
  k_node_gemm<<<((NN + 127) / 128) * 4, 256, 0, stream>>>(agg, w2t, b2, deg, out, sums);
  k_bn_apply<<<(NN * OC / 4 + 255) / 256, 256, 0, stream>>>(out, sums, gamma, beta);
}